// Round 4
// baseline (127.488 us; speedup 1.0000x reference)
//
#include <hip/hip_runtime.h>
#include <math.h>

// Problem constants (from reference setup_inputs)
static constexpr int B_ = 32;    // batch
static constexpr int T_ = 336;   // time
static constexpr int C_ = 7;     // channels (m)
static constexpr int PB = 140;   // 4 banks * 35 cols per batch row
// d_out layout: out[32*10] | dists[32*140] | probs[32*140] | loss[1]
static constexpr int DIST_OFF = 320;
static constexpr int PROB_OFF = 320 + 4480;   // 4800
static constexpr int LOSS_OFF = 9280;

// 8 window-chunks per (b,m), spread over the 4 banks for near-equal work.
// chunk: 0:bank0[0,303) 1:bank1[0,135) 2:bank1[135,269) 3:bank2[0,118)
//        4:bank2[118,236) 5:bank3[0,57) 6:bank3[57,114) 7:bank3[114,169)
__constant__ int c_bank[8] = {0, 1, 1, 2, 2, 3, 3, 3};
__constant__ int c_t0[8]   = {0, 0, 135, 0, 118, 0, 57, 114};
__constant__ int c_t1[8]   = {303, 135, 269, 118, 236, 57, 114, 169};

static constexpr int GRID = 32 * 7 * 8;   // 1792 blocks

// Distance scan over window range [t0,t1), all 5 shapelets of one bank/channel.
// xs[t+j]: one LDS read reused 5x; w[*][j]: wave-uniform -> scalar loads.
// Publishes min of SUM |diff| (uint bits) via global atomicMin.
template <int L>
__device__ __forceinline__ void dist_range(const float* __restrict__ xs,
                                           const float* __restrict__ w,
                                           int m, int t0, int t1,
                                           int bank, int b,
                                           unsigned* __restrict__ gmin)
{
    const int tid  = threadIdx.x;
    const int lane = tid & 63;

    const float* __restrict__ w0 = w + (0 * C_ + m) * L;
    const float* __restrict__ w1 = w + (1 * C_ + m) * L;
    const float* __restrict__ w2 = w + (2 * C_ + m) * L;
    const float* __restrict__ w3 = w + (3 * C_ + m) * L;
    const float* __restrict__ w4 = w + (4 * C_ + m) * L;

    float b0 = INFINITY, b1 = INFINITY, b2 = INFINITY, b3 = INFINITY, b4 = INFINITY;
    for (int t = t0 + tid; t < t1; t += 256) {
        float a0 = 0.f, a1 = 0.f, a2 = 0.f, a3 = 0.f, a4 = 0.f;
        #pragma unroll 8
        for (int j = 0; j < L; ++j) {
            const float xv = xs[t + j];
            a0 += fabsf(xv - w0[j]);
            a1 += fabsf(xv - w1[j]);
            a2 += fabsf(xv - w2[j]);
            a3 += fabsf(xv - w3[j]);
            a4 += fabsf(xv - w4[j]);
        }
        b0 = fminf(b0, a0); b1 = fminf(b1, a1); b2 = fminf(b2, a2);
        b3 = fminf(b3, a3); b4 = fminf(b4, a4);
    }
    #pragma unroll
    for (int off = 32; off; off >>= 1) {
        b0 = fminf(b0, __shfl_down(b0, off, 64));
        b1 = fminf(b1, __shfl_down(b1, off, 64));
        b2 = fminf(b2, __shfl_down(b2, off, 64));
        b3 = fminf(b3, __shfl_down(b3, off, 64));
        b4 = fminf(b4, __shfl_down(b4, off, 64));
    }
    if (lane == 0) {   // non-negative (or +inf from idle waves): uint order == float order
        const int base = (bank * 35 + m) * 32 + b;   // slot = (bank*35 + n*7 + m)*32 + b
        atomicMin(&gmin[base + (0 * C_) * 32], __float_as_uint(b0));
        atomicMin(&gmin[base + (1 * C_) * 32], __float_as_uint(b1));
        atomicMin(&gmin[base + (2 * C_) * 32], __float_as_uint(b2));
        atomicMin(&gmin[base + (3 * C_) * 32], __float_as_uint(b3));
        atomicMin(&gmin[base + (4 * C_) * 32], __float_as_uint(b4));
    }
}

__global__ __launch_bounds__(256, 6)
void k_fused(const float* __restrict__ x,
             const float* __restrict__ w0, const float* __restrict__ w1,
             const float* __restrict__ w2, const float* __restrict__ w3,
             const float* __restrict__ W_out,
             float* __restrict__ out,
             unsigned* __restrict__ gmin,      // d_ws[0:4480]: min-sum bits
             unsigned* __restrict__ counter)   // d_ws[4480]: election counter
{
    __shared__ float xs[T_];
    __shared__ float red[8];
    __shared__ int   lastFlag;
    __shared__ float pS[32 * PB];    // epilogue: probs staged for GEMV (17.9 KB)

    const int bid   = blockIdx.x;    // 1792 = 32 * 7 * 8
    const int b     = bid / 56;
    const int rem   = bid % 56;
    const int m     = rem / 8;
    const int chunk = rem % 8;
    const int tid   = threadIdx.x;
    const int lane  = tid & 63;
    const int wv    = tid >> 6;

    // ---- load channel row: x[b, t, m], stride C_ ----
    const float* __restrict__ xb = x + (size_t)b * T_ * C_ + m;
    for (int t = tid; t < T_; t += 256) xs[t] = xb[(size_t)t * C_];
    __syncthreads();

    // ---- two-pass normalize (ddof=1); identical fp math across a (b,m)'s chunks ----
    float s = 0.f;
    for (int t = tid; t < T_; t += 256) s += xs[t];
    #pragma unroll
    for (int off = 32; off; off >>= 1) s += __shfl_down(s, off, 64);
    if (lane == 0) red[wv] = s;
    __syncthreads();
    const float mu = (red[0] + red[1] + red[2] + red[3]) / (float)T_;

    float q = 0.f;
    for (int t = tid; t < T_; t += 256) { float d = xs[t] - mu; q += d * d; }
    #pragma unroll
    for (int off = 32; off; off >>= 1) q += __shfl_down(q, off, 64);
    if (lane == 0) red[4 + wv] = q;
    __syncthreads();
    const float sd  = sqrtf((red[4] + red[5] + red[6] + red[7]) / (float)(T_ - 1));
    const float inv = 1.f / (sd + 1e-8f);
    for (int t = tid; t < T_; t += 256) xs[t] = (xs[t] - mu) * inv;
    __syncthreads();

    // ---- this chunk's bank / window range ----
    const int bank = c_bank[chunk], t0 = c_t0[chunk], t1 = c_t1[chunk];
    switch (bank) {
        case 0:  dist_range<34 >(xs, w0, m, t0, t1, 0, b, gmin); break;
        case 1:  dist_range<68 >(xs, w1, m, t0, t1, 1, b, gmin); break;
        case 2:  dist_range<101>(xs, w2, m, t0, t1, 2, b, gmin); break;
        default: dist_range<168>(xs, w3, m, t0, t1, 3, b, gmin); break;
    }

    // ---- last-block election ----
    __syncthreads();                 // all waves' atomicMins drained (vmcnt) before counting
    if (tid == 0) {
        __threadfence();
        lastFlag = (atomicAdd(counter, 1u) == (unsigned)(GRID - 1)) ? 1 : 0;
    }
    __syncthreads();
    if (!lastFlag) return;

    // ================= epilogue (one block) =================
    __threadfence();
    // sums -> d, p; write dists/probs; stage p in LDS
    for (int i = tid; i < 32 * PB; i += 256) {
        const int col = i >> 5;           // 0..139
        const int bb  = i & 31;           // 0..31
        const unsigned u = __hip_atomic_load(&gmin[i], __ATOMIC_RELAXED,
                                             __HIP_MEMORY_SCOPE_AGENT);
        const int bk = col / 35;
        const int l  = (bk == 0) ? 34 : (bk == 1) ? 68 : (bk == 2) ? 101 : 168;
        const float d = __uint_as_float(u) / (float)l;   // min-sum -> min-mean
        const float p = expf(-d * d);                    // EPS_GATE = 1.0
        out[DIST_OFF + bb * PB + col] = d;
        out[PROB_OFF + bb * PB + col] = p;
        pS[bb * PB + col] = p;
    }
    __syncthreads();

    // out[b,k] = probs[b,:] . W_out[k,:]
    for (int i = tid; i < 320; i += 256) {
        const int bb = i / 10, k = i % 10;
        const float* __restrict__ pb = pS + bb * PB;
        const float* __restrict__ wk = W_out + k * PB;
        float acc = 0.f;
        #pragma unroll 4
        for (int j = 0; j < PB; ++j) acc += pb[j] * wk[j];
        out[bb * 10 + k] = acc;
    }

    // loss = 0.1 * mean|W_out| (1400 elems)
    float ls = 0.f;
    for (int j = tid; j < 1400; j += 256) ls += fabsf(W_out[j]);
    #pragma unroll
    for (int off = 32; off; off >>= 1) ls += __shfl_down(ls, off, 64);
    if (lane == 0) red[wv] = ls;
    __syncthreads();
    if (tid == 0)
        out[LOSS_OFF] = 0.1f * (red[0] + red[1] + red[2] + red[3]) / 1400.0f;
}

extern "C" void kernel_launch(void* const* d_in, const int* in_sizes, int n_in,
                              void* d_out, int out_size, void* d_ws, size_t ws_size,
                              hipStream_t stream)
{
    const float* x     = (const float*)d_in[0];
    const float* w0    = (const float*)d_in[1];
    const float* w1    = (const float*)d_in[2];
    const float* w2    = (const float*)d_in[3];
    const float* w3    = (const float*)d_in[4];
    const float* W_out = (const float*)d_in[5];
    float*    out  = (float*)d_out;
    unsigned* gmin = (unsigned*)d_ws;            // 4480 slots
    unsigned* cnt  = gmin + 32 * PB;             // 1 slot

    // init min-slots to 0xFFFFFFFF (> any finite-sum bits) and counter to 0
    hipMemsetAsync(gmin, 0xFF, 32 * PB * sizeof(unsigned), stream);
    hipMemsetAsync(cnt, 0, sizeof(unsigned), stream);
    hipLaunchKernelGGL(k_fused, dim3(GRID), dim3(256), 0, stream,
                       x, w0, w1, w2, w3, W_out, out, gmin, cnt);
}

// Round 5
// 106.525 us; speedup vs baseline: 1.1968x; 1.1968x over previous
//
#include <hip/hip_runtime.h>
#include <math.h>

// Problem constants (from reference setup_inputs)
static constexpr int B_ = 32;    // batch
static constexpr int T_ = 336;   // time
static constexpr int C_ = 7;     // channels (m)
static constexpr int PB = 140;   // 4 banks * 35 cols per batch row
// d_out layout: out[32*10] | dists[32*140] | probs[32*140] | loss[1]
static constexpr int DIST_OFF = 320;
static constexpr int PROB_OFF = 320 + 4480;   // 4800
static constexpr int LOSS_OFF = 9280;

static constexpr int GRID = 32 * 7 * 2;   // 448 blocks: (b, m, half)

// ---------------------------------------------------------------------------
// One wave-task: windows [ws, ws+count) of one bank, W contiguous windows per
// lane via sliding registers. Inner loop touches ONLY LDS + VALU:
//   - x: 1 ds_read per j (lane stride W: 1/2/3/5 -> <=2-way conflict, free)
//   - w: row wT[j][0..4] (row stride 8 floats, 16B aligned -> b128+b32),
//        same address all lanes -> broadcast
// Publishes min-of-sum via global atomicMin (uint bits, non-negative floats).
// ---------------------------------------------------------------------------
template <int L, int W>
__device__ __forceinline__ void dist_task(const float* __restrict__ xs,
                                          const float* __restrict__ wT,
                                          int ws, int count,
                                          unsigned* __restrict__ gmin,
                                          int slotBase)   // (bank*35+m)*32+b
{
    const int lane = threadIdx.x & 63;
    int start = ws + W * lane;
    const int smax = ws + count - W;          // count >= W for all tasks
    if (start > smax) start = smax;           // clamped lanes recompute dups

    float xv[W];
    #pragma unroll
    for (int k = 0; k < W; ++k) xv[k] = xs[start + k];

    float acc[5][W];
    #pragma unroll
    for (int n = 0; n < 5; ++n)
        #pragma unroll
        for (int k = 0; k < W; ++k) acc[n][k] = 0.f;

    #pragma unroll 4
    for (int j = 0; j < L; ++j) {
        const float wa = wT[j * 8 + 0];
        const float wb = wT[j * 8 + 1];
        const float wc = wT[j * 8 + 2];
        const float wd = wT[j * 8 + 3];
        const float we = wT[j * 8 + 4];
        #pragma unroll
        for (int k = 0; k < W; ++k) {
            const float xk = xv[k];
            acc[0][k] += fabsf(xk - wa);
            acc[1][k] += fabsf(xk - wb);
            acc[2][k] += fabsf(xk - wc);
            acc[3][k] += fabsf(xk - wd);
            acc[4][k] += fabsf(xk - we);
        }
        // slide window set one step right (reads up to xs[336]; xs padded)
        #pragma unroll
        for (int k = 0; k < W - 1; ++k) xv[k] = xv[k + 1];
        xv[W - 1] = xs[start + j + W];
    }

    #pragma unroll
    for (int n = 0; n < 5; ++n) {
        float bn = acc[n][0];
        #pragma unroll
        for (int k = 1; k < W; ++k) bn = fminf(bn, acc[n][k]);
        #pragma unroll
        for (int off = 32; off; off >>= 1)
            bn = fminf(bn, __shfl_down(bn, off, 64));
        if (lane == 0)
            atomicMin(&gmin[slotBase + n * 224], __float_as_uint(bn));
    }
}

// ---------------------------------------------------------------------------
// Grid: (b, m, half). Each block: load+normalize channel row (redundant but
// deterministic across the pair), stage its banks' w transposed into LDS,
// then its 4 waves run pre-balanced window-tasks (~850-1020 lane-ops each):
//   half 0: bank0[all,W5] | bank1[0,192)W3 | bank1[192,269)W3 | bank2[0,128)W2
//   half 1: bank2[128,236)W2 | bank3[0,64)W1 | bank3[64,128)W1 | bank3[128,169)W1
// Last block (global election) converts min-sums -> dists/probs, does the
// output GEMV and the loss.
// ---------------------------------------------------------------------------
__global__ __launch_bounds__(256)
void k_fused(const float* __restrict__ x,
             const float* __restrict__ w0, const float* __restrict__ w1,
             const float* __restrict__ w2, const float* __restrict__ w3,
             const float* __restrict__ W_out,
             float* __restrict__ out,
             unsigned* __restrict__ gmin,      // d_ws[0:4480]
             unsigned* __restrict__ counter)   // d_ws[4480]
{
    __shared__ float xs[344];                  // 336 + slide pad
    __shared__ float wT[2152];                 // transposed w rows, stride 8
    __shared__ float red[8];
    __shared__ int   lastFlag;
    __shared__ float pS[32 * PB];              // epilogue GEMV staging

    const int bid  = blockIdx.x;               // 448
    const int b    = bid / 14;
    const int rem  = bid % 14;
    const int m    = rem >> 1;
    const int h    = rem & 1;
    const int tid  = threadIdx.x;
    const int lane = tid & 63;
    const int wv   = tid >> 6;

    // ---- load channel row x[b, :, m] (stride C_) + zero the slide pad ----
    const float* __restrict__ xb = x + (size_t)b * T_ * C_ + m;
    for (int t = tid; t < 344; t += 256)
        xs[t] = (t < T_) ? xb[(size_t)t * C_] : 0.f;

    // ---- stage this half's w banks, transposed: wT[j*8+n] = w[n][m][j] ----
    {
        const float* srcA; const float* srcB; const float* srcC;
        int LA, LB, LC, oA, oB, oC;
        if (h == 0) { srcA = w0 + m * 34;  LA = 34;  oA = 0;
                      srcB = w1 + m * 68;  LB = 68;  oB = 34 * 8;
                      srcC = w2 + m * 101; LC = 101; oC = (34 + 68) * 8; }
        else        { srcA = w2 + m * 101; LA = 101; oA = 0;
                      srcB = w3 + m * 168; LB = 168; oB = 101 * 8;
                      srcC = nullptr;      LC = 0;   oC = 0; }
        for (int i = tid; i < 5 * LA; i += 256) {
            int n = i / LA, j = i - n * LA;
            wT[oA + j * 8 + n] = srcA[(size_t)n * C_ * LA + j];
        }
        for (int i = tid; i < 5 * LB; i += 256) {
            int n = i / LB, j = i - n * LB;
            wT[oB + j * 8 + n] = srcB[(size_t)n * C_ * LB + j];
        }
        for (int i = tid; i < 5 * LC; i += 256) {
            int n = i / LC, j = i - n * LC;
            wT[oC + j * 8 + n] = srcC[(size_t)n * C_ * LC + j];
        }
    }
    __syncthreads();

    // ---- two-pass normalize (ddof=1); identical fp math for both halves ----
    float s = 0.f;
    for (int t = tid; t < T_; t += 256) s += xs[t];
    #pragma unroll
    for (int off = 32; off; off >>= 1) s += __shfl_down(s, off, 64);
    if (lane == 0) red[wv] = s;
    __syncthreads();
    const float mu = (red[0] + red[1] + red[2] + red[3]) / (float)T_;

    float q = 0.f;
    for (int t = tid; t < T_; t += 256) { float d = xs[t] - mu; q += d * d; }
    #pragma unroll
    for (int off = 32; off; off >>= 1) q += __shfl_down(q, off, 64);
    if (lane == 0) red[4 + wv] = q;
    __syncthreads();
    const float sd  = sqrtf((red[4] + red[5] + red[6] + red[7]) / (float)(T_ - 1));
    const float inv = 1.f / (sd + 1e-8f);
    for (int t = tid; t < T_; t += 256) xs[t] = (xs[t] - mu) * inv;
    __syncthreads();

    // ---- balanced wave-tasks ----
    const int sb0 = (0 * 35 + m) * 32 + b;   // slotBase per bank
    const int sb1 = (1 * 35 + m) * 32 + b;
    const int sb2 = (2 * 35 + m) * 32 + b;
    const int sb3 = (3 * 35 + m) * 32 + b;
    if (h == 0) {
        switch (wv) {
            case 0: dist_task<34, 5>(xs, wT,                 0, 303, gmin, sb0); break;
            case 1: dist_task<68, 3>(xs, wT + 34 * 8,        0, 192, gmin, sb1); break;
            case 2: dist_task<68, 3>(xs, wT + 34 * 8,      192,  77, gmin, sb1); break;
            default:dist_task<101,2>(xs, wT + (34 + 68) * 8, 0, 128, gmin, sb2); break;
        }
    } else {
        switch (wv) {
            case 0: dist_task<101,2>(xs, wT,           128, 108, gmin, sb2); break;
            case 1: dist_task<168,1>(xs, wT + 101 * 8,   0,  64, gmin, sb3); break;
            case 2: dist_task<168,1>(xs, wT + 101 * 8,  64,  64, gmin, sb3); break;
            default:dist_task<168,1>(xs, wT + 101 * 8, 128,  41, gmin, sb3); break;
        }
    }

    // ---- last-block election ----
    __syncthreads();
    if (tid == 0) {
        __threadfence();
        lastFlag = (atomicAdd(counter, 1u) == (unsigned)(GRID - 1)) ? 1 : 0;
    }
    __syncthreads();
    if (!lastFlag) return;

    // ================= epilogue (one block) =================
    __threadfence();
    for (int i = tid; i < 32 * PB; i += 256) {
        const int col = i >> 5;           // 0..139
        const int bb  = i & 31;           // 0..31
        const unsigned u = __hip_atomic_load(&gmin[i], __ATOMIC_RELAXED,
                                             __HIP_MEMORY_SCOPE_AGENT);
        const int bk = col / 35;
        const int l  = (bk == 0) ? 34 : (bk == 1) ? 68 : (bk == 2) ? 101 : 168;
        const float d = __uint_as_float(u) / (float)l;   // min-sum -> min-mean
        const float p = expf(-d * d);                    // EPS_GATE = 1.0
        out[DIST_OFF + bb * PB + col] = d;
        out[PROB_OFF + bb * PB + col] = p;
        pS[bb * PB + col] = p;
    }
    __syncthreads();

    // out[b,k] = probs[b,:] . W_out[k,:]
    for (int i = tid; i < 320; i += 256) {
        const int bb = i / 10, k = i % 10;
        const float* __restrict__ pb = pS + bb * PB;
        const float* __restrict__ wk = W_out + k * PB;
        float acc = 0.f;
        #pragma unroll 4
        for (int j = 0; j < PB; ++j) acc += pb[j] * wk[j];
        out[bb * 10 + k] = acc;
    }

    // loss = 0.1 * mean|W_out| (1400 elems)
    float ls = 0.f;
    for (int j = tid; j < 1400; j += 256) ls += fabsf(W_out[j]);
    #pragma unroll
    for (int off = 32; off; off >>= 1) ls += __shfl_down(ls, off, 64);
    __syncthreads();
    if (lane == 0) red[wv] = ls;
    __syncthreads();
    if (tid == 0)
        out[LOSS_OFF] = 0.1f * (red[0] + red[1] + red[2] + red[3]) / 1400.0f;
}

extern "C" void kernel_launch(void* const* d_in, const int* in_sizes, int n_in,
                              void* d_out, int out_size, void* d_ws, size_t ws_size,
                              hipStream_t stream)
{
    const float* x     = (const float*)d_in[0];
    const float* w0    = (const float*)d_in[1];
    const float* w1    = (const float*)d_in[2];
    const float* w2    = (const float*)d_in[3];
    const float* w3    = (const float*)d_in[4];
    const float* W_out = (const float*)d_in[5];
    float*    out  = (float*)d_out;
    unsigned* gmin = (unsigned*)d_ws;            // 4480 slots
    unsigned* cnt  = gmin + 32 * PB;             // 1 slot

    hipMemsetAsync(gmin, 0xFF, 32 * PB * sizeof(unsigned), stream);
    hipMemsetAsync(cnt, 0, sizeof(unsigned), stream);
    hipLaunchKernelGGL(k_fused, dim3(GRID), dim3(256), 0, stream,
                       x, w0, w1, w2, w3, W_out, out, gmin, cnt);
}